// Round 6
// baseline (7087.832 us; speedup 1.0000x reference)
//
#include <hip/hip_runtime.h>
#include <hip/hip_fp16.h>
#include <math.h>

// Problem constants
#define S1 256
#define S2 256
#define S3 128
#define DV 8
#define NK1 30
#define NK2 30
#define NK3 20
#define NPEN (S1*S2)          // 65536 pencils along x3
#define PENC (S3*DV)          // 1024 elements per v pencil (fp16)
#define GPEN (DV*NK3)         // 160 complex per g pencil (fp16 complex)
#define HSLICE (NK2*DV*NK3)   // 4800 complex per x1 slice of h (fp32)
#define PB 4                  // pencils per block in combine/shallow/final

// vnf LDS layout: [PB][DV][VNF_D] floats, parity plane at par*VNF_P
#define VNF_D 148
#define VNF_P 72

// Workspace layout in float-slots (4 bytes each) — total ~179.7 MiB
#define OFF_V     0ull
#define SZ_V      ((unsigned long long)NPEN*PENC/2)
#define OFF_G     (OFF_V + SZ_V)
#define SZ_G      ((unsigned long long)NPEN*GPEN)
#define OFF_H     (OFF_G + SZ_G)
#define SZ_H      ((unsigned long long)S1*HSLICE*2)
#define OFF_F     (OFF_H + SZ_H)
#define SZ_F      ((unsigned long long)NK1*HSLICE*2)
#define OFF_RF    (OFF_F + SZ_F)
#define OFF_TW128 (OFF_RF + SZ_F)
#define SZ_TW128  (2ull*NK3*64)
#define OFF_TW256 (OFF_TW128 + SZ_TW128)

__device__ __forceinline__ float gelu_f(float x){
  return 0.5f*x*(1.0f+erff(x*0.70710678118654752440f));
}
__device__ __forceinline__ void cmac_fwd(float& ar, float& ai, float2 a, float2 t){
  ar = fmaf(a.x, t.x, ar); ar = fmaf(-a.y, t.y, ar);
  ai = fmaf(a.x, t.y, ai); ai = fmaf(a.y, t.x, ai);
}
__device__ __forceinline__ void cmac_inv(float& ar, float& ai, float2 a, float2 t){
  ar = fmaf(a.x, t.x, ar); ar = fmaf(a.y, t.y, ar);
  ai = fmaf(a.y, t.x, ai); ai = fmaf(-a.x, t.y, ai);
}
// exchange an 8-byte packet with lane l^32 (full 64-lane wave)
__device__ __forceinline__ uint2 xor32_u2(uint2 a){
  uint2 r;
  r.x = (unsigned)__shfl_xor((int)a.x, 32);
  r.y = (unsigned)__shfl_xor((int)a.y, 32);
  return r;
}

// ---------------------------------------------------------------- twiddles
// tw128: [20][64] e^{-2pi i k x/128}, x<64 ; tw256: [30][256]
__global__ __launch_bounds__(256) void k_twiddles(float2* __restrict__ tw128,
                                                  float2* __restrict__ tw256){
  int idx = blockIdx.x*256 + threadIdx.x;
  if (idx < NK3*64){
    int k = idx >> 6, x = idx & 63;
    int m = (k*x) & 127;
    float a = -(float)m * (1.0f/64.0f);
    float s, c; sincospif(a, &s, &c);
    tw128[idx] = make_float2(c, s);   // (cos, -sin)
  }
  int j = idx - NK3*64;
  if (j >= 0 && j < NK2*S2){
    int k = j >> 8, x = j & 255;
    int m = (k*x) & 255;
    float a = -(float)m * (1.0f/128.0f);
    float s, c; sincospif(a, &s, &c);
    tw256[j] = make_float2(c, s);
  }
}

// =========================================================================
// fwd axis-2 DFT from folded vnf -> g, lanes 0..39 of each warp
// X[k3] = sum_{x<64} w_par[x] e^{-2pi i k3 x/128},  par = k3&1
// =========================================================================
__device__ __forceinline__ void fwd_dft_phase(const float (*vnfp)[VNF_D],
    const float2* tws, __half2* gout_pen, int l){
  if (l >= 40) return;
  int k3 = l % 20, dg = l / 20, par = k3 & 1;
  float ar[4] = {0,0,0,0}, ai[4] = {0,0,0,0};
  for (int x0 = 0; x0 < 64; x0 += 4){
    float4 vv[4];
    #pragma unroll
    for (int di=0; di<4; di++)
      vv[di] = *reinterpret_cast<const float4*>(&vnfp[dg*4+di][par*VNF_P + x0]);
    float2 t2[4];
    #pragma unroll
    for (int xi=0; xi<4; xi++) t2[xi] = tws[k3*67 + x0 + xi];
    #pragma unroll
    for (int di=0; di<4; di++){
      ar[di] = fmaf(vv[di].x, t2[0].x, ar[di]); ai[di] = fmaf(vv[di].x, t2[0].y, ai[di]);
      ar[di] = fmaf(vv[di].y, t2[1].x, ar[di]); ai[di] = fmaf(vv[di].y, t2[1].y, ai[di]);
      ar[di] = fmaf(vv[di].z, t2[2].x, ar[di]); ai[di] = fmaf(vv[di].z, t2[2].y, ai[di]);
      ar[di] = fmaf(vv[di].w, t2[3].x, ar[di]); ai[di] = fmaf(vv[di].w, t2[3].y, ai[di]);
    }
  }
  #pragma unroll
  for (int di=0; di<4; di++)
    gout_pen[(dg*4+di)*NK3 + k3] = __floats2half2_rn(ar[di], ai[di]);
}

// store v: lane l packs its 8B (e0 half) per q, swaps with lane l^32, and
// lanes<32 write q=0,1 / lanes>=32 write q=2,3 as full 16B contiguous chunks
__device__ __forceinline__ void store_v_swap(const float val[4][4],
    __half* vpen, int l, int xb){
  uint2 pk[4], ot[4];
  #pragma unroll
  for (int q=0; q<4; q++){
    union { uint2 u2; __half2 h2[2]; } u;
    u.h2[0] = __floats2half2_rn(val[q][0], val[q][1]);
    u.h2[1] = __floats2half2_rn(val[q][2], val[q][3]);
    pk[q] = u.u2;
  }
  #pragma unroll
  for (int q=0; q<4; q++) ot[q] = xor32_u2(pk[q]);
  int hi = l >> 5;
  #pragma unroll
  for (int qq=0; qq<2; qq++){
    int q = qq + hi*2;
    int x3 = xb + 32*q;
    uint4 full = hi ? make_uint4(ot[q].x, ot[q].y, pk[q].x, pk[q].y)
                    : make_uint4(pk[q].x, pk[q].y, ot[q].x, ot[q].y);
    *reinterpret_cast<uint4*>(vpen + x3*DV) = full;
  }
}

// ------------------------------------------------- shallow lift + axis-2 DFT
__global__ __launch_bounds__(256,4) void k_shallow(const float* __restrict__ x,
    const float* __restrict__ sw, const float* __restrict__ sb,
    __half* __restrict__ v, __half2* __restrict__ g,
    const float2* __restrict__ twg){
  __shared__ float2 tws[NK3*67];
  __shared__ float  vnf[PB][DV][VNF_D];
  int t = threadIdx.x;
  size_t pen_base = (size_t)blockIdx.x * PB;
  for (int i=t; i<NK3*64; i+=256){ int k=i>>6, xx=i&63; tws[k*67+xx] = twg[i]; }
  int p = t >> 6, l = t & 63;
  int xb = l & 31, e0 = (l >> 5)*4;
  size_t pen = pen_base + p;
  float swr[4], sbr[4];
  #pragma unroll
  for (int j=0;j<4;j++){ swr[j] = sw[e0+j]; sbr[j] = sb[e0+j]; }
  float val[4][4];
  #pragma unroll
  for (int q=0; q<4; q++){
    int x3 = xb + 32*q;
    float xv = x[(pen<<7) + x3];
    #pragma unroll
    for (int j=0;j<4;j++) val[q][j] = gelu_f(fmaf(xv, swr[j], sbr[j]));
  }
  store_v_swap(val, v + (pen<<10), l, xb);
  #pragma unroll
  for (int j=0;j<4;j++){
    vnf[p][e0+j][xb]             = val[0][j] + val[2][j];
    vnf[p][e0+j][VNF_P + xb]     = val[0][j] - val[2][j];
    vnf[p][e0+j][xb+32]          = val[1][j] + val[3][j];
    vnf[p][e0+j][VNF_P + xb+32]  = val[1][j] - val[3][j];
  }
  __syncthreads();
  fwd_dft_phase(vnf[p], tws, g + pen*GPEN, l);
}

// --------------------- combine: inv axis-2 DFT + skip + GELU + next fwd DFT
__global__ __launch_bounds__(256,4) void k_combine(__half* __restrict__ v,
    __half2* __restrict__ g, const float* __restrict__ w,
    const float2* __restrict__ twg){
  __shared__ float2 tws[NK3*67];
  __shared__ float  vnf[PB][DV][VNF_D];
  __shared__ float2 Gsm[PB][GPEN];
  __shared__ float  wsm[64];
  int t = threadIdx.x;
  size_t pen_base = (size_t)blockIdx.x * PB;
  for (int i=t; i<NK3*64; i+=256){ int k=i>>6, xx=i&63; tws[k*67+xx] = twg[i]; }
  {
    const __half2* gsrc = g + pen_base*GPEN;
    float2* Gf = &Gsm[0][0];
    for (int i=t; i<PB*GPEN; i+=256){
      float2 gv = __half22float2(gsrc[i]);
      if (i % 20){ gv.x *= 2.0f; gv.y *= 2.0f; }   // irfft factor 2, k3>0
      Gf[i] = gv;
    }
  }
  if (t < 64) wsm[t] = w[t];
  __syncthreads();

  int p = t >> 6, l = t & 63;
  int xb = l & 31, e0 = (l >> 5)*4;
  size_t pen = pen_base + p;
  float wr[DV][4];
  #pragma unroll
  for (int d=0; d<DV; d++)
    #pragma unroll
    for (int j=0; j<4; j++) wr[d][j] = wsm[d*DV + e0 + j];

  // inverse axis-2 with parity fold: E = even k3 (incl DC), O = odd k3
  float E[2][4], O[2][4];
  #pragma unroll
  for (int xi=0; xi<2; xi++)
    #pragma unroll
    for (int j=0; j<4; j++){ E[xi][j] = Gsm[p][(e0+j)*NK3].x; O[xi][j] = 0.f; }
  #pragma unroll
  for (int k3=1; k3<NK3; k3++){
    float2 c0 = tws[k3*67 + xb];
    float2 c1 = tws[k3*67 + xb + 32];
    float2 gq[4];
    #pragma unroll
    for (int j=0; j<4; j++) gq[j] = Gsm[p][(e0+j)*NK3 + k3];
    if (k3 & 1){
      #pragma unroll
      for (int j=0; j<4; j++){
        O[0][j] = fmaf(gq[j].x, c0.x, O[0][j]); O[0][j] = fmaf(gq[j].y, c0.y, O[0][j]);
        O[1][j] = fmaf(gq[j].x, c1.x, O[1][j]); O[1][j] = fmaf(gq[j].y, c1.y, O[1][j]);
      }
    } else {
      #pragma unroll
      for (int j=0; j<4; j++){
        E[0][j] = fmaf(gq[j].x, c0.x, E[0][j]); E[0][j] = fmaf(gq[j].y, c0.y, E[0][j]);
        E[1][j] = fmaf(gq[j].x, c1.x, E[1][j]); E[1][j] = fmaf(gq[j].y, c1.y, E[1][j]);
      }
    }
  }
  // skip + gelu ; q: x3 = xb+32q
  float val[4][4];
  #pragma unroll
  for (int q=0; q<4; q++){
    int x3 = xb + 32*q;
    union { uint4 u4; __half2 h2[4]; } lk;
    lk.u4 = *reinterpret_cast<const uint4*>(v + (pen<<10) + x3*DV);
    float vv[8];
    #pragma unroll
    for (int qq=0; qq<4; qq++){
      float2 f2 = __half22float2(lk.h2[qq]);
      vv[2*qq] = f2.x; vv[2*qq+1] = f2.y;
    }
    float s[4];
    #pragma unroll
    for (int j=0; j<4; j++){
      float e = E[q&1][j], o = O[q&1][j];
      s[j] = (q < 2) ? (e + o) : (e - o);
    }
    #pragma unroll
    for (int d=0; d<DV; d++)
      #pragma unroll
      for (int j=0; j<4; j++) s[j] = fmaf(vv[d], wr[d][j], s[j]);
    #pragma unroll
    for (int j=0; j<4; j++) val[q][j] = gelu_f(s[j]);
  }
  store_v_swap(val, v + (pen<<10), l, xb);
  // post-gelu parity fold for next fwd DFT
  #pragma unroll
  for (int j=0; j<4; j++){
    vnf[p][e0+j][xb]            = val[0][j] + val[2][j];
    vnf[p][e0+j][VNF_P + xb]    = val[0][j] - val[2][j];
    vnf[p][e0+j][xb+32]         = val[1][j] + val[3][j];
    vnf[p][e0+j][VNF_P + xb+32] = val[1][j] - val[3][j];
  }
  __syncthreads();
  fwd_dft_phase(vnf[p], tws, g + pen*GPEN, l);
}

// --------------------- final: inv axis-2 DFT + skip + GELU + projection
__global__ __launch_bounds__(256,3) void k_final(const __half* __restrict__ v,
    const __half2* __restrict__ g, const float* __restrict__ w,
    const float* __restrict__ pw, const float* __restrict__ pb,
    float* __restrict__ out, const float2* __restrict__ twg){
  __shared__ float2 tws[NK3*67];
  __shared__ float  vnr[PB][DV][128];
  __shared__ float2 Gsm[PB][GPEN];
  __shared__ float  wsm[64];
  __shared__ float  pws[DV];
  __shared__ float  pbs;
  int t = threadIdx.x;
  size_t pen_base = (size_t)blockIdx.x * PB;
  for (int i=t; i<NK3*64; i+=256){ int k=i>>6, xx=i&63; tws[k*67+xx] = twg[i]; }
  {
    const __half2* gsrc = g + pen_base*GPEN;
    float2* Gf = &Gsm[0][0];
    for (int i=t; i<PB*GPEN; i+=256){
      float2 gv = __half22float2(gsrc[i]);
      if (i % 20){ gv.x *= 2.0f; gv.y *= 2.0f; }
      Gf[i] = gv;
    }
  }
  if (t < 64) wsm[t] = w[t];
  else if (t < 64+DV) pws[t-64] = pw[t-64];
  else if (t == 64+DV) pbs = pb[0];
  __syncthreads();

  int p = t >> 6, l = t & 63;
  int xb = l & 31, e0 = (l >> 5)*4;
  size_t pen = pen_base + p;
  float wr[DV][4];
  #pragma unroll
  for (int d=0; d<DV; d++)
    #pragma unroll
    for (int j=0; j<4; j++) wr[d][j] = wsm[d*DV + e0 + j];

  float E[2][4], O[2][4];
  #pragma unroll
  for (int xi=0; xi<2; xi++)
    #pragma unroll
    for (int j=0; j<4; j++){ E[xi][j] = Gsm[p][(e0+j)*NK3].x; O[xi][j] = 0.f; }
  #pragma unroll
  for (int k3=1; k3<NK3; k3++){
    float2 c0 = tws[k3*67 + xb];
    float2 c1 = tws[k3*67 + xb + 32];
    float2 gq[4];
    #pragma unroll
    for (int j=0; j<4; j++) gq[j] = Gsm[p][(e0+j)*NK3 + k3];
    if (k3 & 1){
      #pragma unroll
      for (int j=0; j<4; j++){
        O[0][j] = fmaf(gq[j].x, c0.x, O[0][j]); O[0][j] = fmaf(gq[j].y, c0.y, O[0][j]);
        O[1][j] = fmaf(gq[j].x, c1.x, O[1][j]); O[1][j] = fmaf(gq[j].y, c1.y, O[1][j]);
      }
    } else {
      #pragma unroll
      for (int j=0; j<4; j++){
        E[0][j] = fmaf(gq[j].x, c0.x, E[0][j]); E[0][j] = fmaf(gq[j].y, c0.y, E[0][j]);
        E[1][j] = fmaf(gq[j].x, c1.x, E[1][j]); E[1][j] = fmaf(gq[j].y, c1.y, E[1][j]);
      }
    }
  }
  #pragma unroll
  for (int q=0; q<4; q++){
    int x3 = xb + 32*q;
    union { uint4 u4; __half2 h2[4]; } lk;
    lk.u4 = *reinterpret_cast<const uint4*>(v + (pen<<10) + x3*DV);
    float vv[8];
    #pragma unroll
    for (int qq=0; qq<4; qq++){
      float2 f2 = __half22float2(lk.h2[qq]);
      vv[2*qq] = f2.x; vv[2*qq+1] = f2.y;
    }
    float s[4];
    #pragma unroll
    for (int j=0; j<4; j++){
      float e = E[q&1][j], o = O[q&1][j];
      s[j] = (q < 2) ? (e + o) : (e - o);
    }
    #pragma unroll
    for (int d=0; d<DV; d++)
      #pragma unroll
      for (int j=0; j<4; j++) s[j] = fmaf(vv[d], wr[d][j], s[j]);
    #pragma unroll
    for (int j=0; j<4; j++) vnr[p][e0+j][x3] = gelu_f(s[j]);
  }
  __syncthreads();
  float pwr[DV];
  #pragma unroll
  for (int e=0; e<DV; e++) pwr[e] = pws[e];
  float pbv = pbs;
  #pragma unroll
  for (int it=0; it<2; it++){
    int p2 = it*2 + (t>>7);
    int x3 = t & 127;
    float acc = pbv;
    #pragma unroll
    for (int e=0; e<DV; e++) acc = fmaf(vnr[p2][e][x3], pwr[e], acc);
    out[((pen_base + p2)<<7) + x3] = acc;
  }
}

// ------------------------------------------------------- axis-1 forward DFT
// grid (S1, 2); parity fold over x2 / x2+128 (chunk c / c+4)
__global__ __launch_bounds__(256) void k_stageB(const __half2* __restrict__ g,
    float2* __restrict__ h, const float2* __restrict__ twg){
  __shared__ unsigned int gsm[2][32*160];   // 40 KB
  int x1 = blockIdx.x;
  int k3o = blockIdx.y * 10;
  int t = threadIdx.x;
  int k2 = t >> 3, d = t & 7;
  float sgn = (k2 & 1) ? -1.0f : 1.0f;
  float ar[10], ai[10];
  #pragma unroll
  for (int j=0;j<10;j++){ ar[j]=0.f; ai[j]=0.f; }
  for (int c = 0; c < 4; c++){
    __syncthreads();
    const uint4* s0 = reinterpret_cast<const uint4*>(g + (size_t)(x1*S2 + c*32)*GPEN);
    const uint4* s1 = reinterpret_cast<const uint4*>(g + (size_t)(x1*S2 + (c+4)*32)*GPEN);
    uint4* d0 = reinterpret_cast<uint4*>(gsm[0]);
    uint4* d1 = reinterpret_cast<uint4*>(gsm[1]);
    #pragma unroll
    for (int r=0; r<5; r++){ d0[r*256 + t] = s0[r*256 + t]; d1[r*256 + t] = s1[r*256 + t]; }
    __syncthreads();
    if (t < 240){
      for (int x2l = 0; x2l < 32; x2l++){
        float2 tw = twg[k2*S2 + c*32 + x2l];
        const uint2* qlo = reinterpret_cast<const uint2*>(&gsm[0][x2l*160 + d*20 + k3o]);
        const uint2* qhi = reinterpret_cast<const uint2*>(&gsm[1][x2l*160 + d*20 + k3o]);
        #pragma unroll
        for (int jj=0; jj<5; jj++){
          uint2 ulo = qlo[jj], uhi = qhi[jj];
          float2 a0 = __half22float2(*reinterpret_cast<const __half2*>(&ulo.x));
          float2 b0 = __half22float2(*reinterpret_cast<const __half2*>(&uhi.x));
          float2 a1 = __half22float2(*reinterpret_cast<const __half2*>(&ulo.y));
          float2 b1 = __half22float2(*reinterpret_cast<const __half2*>(&uhi.y));
          float2 g0 = make_float2(fmaf(sgn, b0.x, a0.x), fmaf(sgn, b0.y, a0.y));
          float2 g1 = make_float2(fmaf(sgn, b1.x, a1.x), fmaf(sgn, b1.y, a1.y));
          cmac_fwd(ar[2*jj],   ai[2*jj],   g0, tw);
          cmac_fwd(ar[2*jj+1], ai[2*jj+1], g1, tw);
        }
      }
    }
  }
  if (t < 240){
    float2* hp = h + (size_t)((x1*NK2 + k2)*(DV*NK3) + d*NK3 + k3o);
    #pragma unroll
    for (int j=0;j<10;j++) hp[j] = make_float2(ar[j], ai[j]);
  }
}

// ------------------------------------------------------- axis-0 forward DFT
// parity fold over x1 / x1+128
__global__ __launch_bounds__(256) void k_stageC(const float2* __restrict__ h,
    float2* __restrict__ f, const float2* __restrict__ tw256){
  int idx = blockIdx.x*256 + threadIdx.x;
  if (idx >= NK1*HSLICE) return;
  int k1 = idx / HSLICE, r = idx % HSLICE;
  float sgn = (k1 & 1) ? -1.0f : 1.0f;
  float ar=0.f, ai=0.f;
  const float2* twp = &tw256[k1*S1];
  for (int x1=0; x1<128; x1++){
    float2 h1 = h[(size_t)x1*HSLICE + r];
    float2 h2 = h[(size_t)(x1+128)*HSLICE + r];
    float2 hv = make_float2(fmaf(sgn, h2.x, h1.x), fmaf(sgn, h2.y, h1.y));
    cmac_fwd(ar, ai, hv, twp[x1]);
  }
  f[idx] = make_float2(ar, ai);
}

// ------------------------------------------------------------- mode mixing
__global__ __launch_bounds__(256) void k_mix(const float2* __restrict__ f,
    const float* __restrict__ Rr, const float* __restrict__ Ri,
    float2* __restrict__ Rf){
  int idx = blockIdx.x*256 + threadIdx.x;
  if (idx >= NK1*HSLICE) return;
  int k12 = idx / (DV*NK3), r = idx % (DV*NK3);
  int e = r / NK3, k3 = r % NK3;
  const float2* fp  = &f[(size_t)k12*(DV*NK3) + k3];
  const float* rrp = &Rr[((size_t)k12*NK3 + k3)*64 + e];
  const float* rip = &Ri[((size_t)k12*NK3 + k3)*64 + e];
  float ar=0.f, ai=0.f;
  #pragma unroll
  for (int d=0; d<DV; d++){
    float2 fv = fp[d*NK3];
    float wr = rrp[d*DV], wi = rip[d*DV];
    ar = fmaf(fv.x, wr, ar); ar = fmaf(-fv.y, wi, ar);
    ai = fmaf(fv.x, wi, ai); ai = fmaf(fv.y, wr, ai);
  }
  const float sc = 1.1920928955078125e-7f; // 1/(256*256*128)
  Rf[idx] = make_float2(ar*sc, ai*sc);
}

// ------------------------------------------------------- axis-0 inverse DFT
// parity fold: one thread emits H[x1] and H[x1+128]
__global__ __launch_bounds__(256) void k_stageCi(const float2* __restrict__ Rf,
    float2* __restrict__ H, const float2* __restrict__ tw256){
  int idx = blockIdx.x*256 + threadIdx.x;   // exactly 128*4800 threads
  int x1 = idx / HSLICE, r = idx % HSLICE;
  float Er=0.f, Ei=0.f, Or=0.f, Oi=0.f;
  #pragma unroll
  for (int k1=0; k1<NK1; k1++){
    float2 a = Rf[(size_t)k1*HSLICE + r];
    float2 tw = tw256[k1*S1 + x1];
    if (k1 & 1) cmac_inv(Or, Oi, a, tw);
    else        cmac_inv(Er, Ei, a, tw);
  }
  H[(size_t)x1*HSLICE + r]        = make_float2(Er+Or, Ei+Oi);
  H[(size_t)(x1+128)*HSLICE + r]  = make_float2(Er-Or, Ei-Oi);
}

// ------------------------------------------------------- axis-1 inverse DFT
// parity fold: one thread-iter emits G[x2] and G[x2+128]
__global__ __launch_bounds__(320) void k_stageBi(const float2* __restrict__ H,
    __half2* __restrict__ G, const float2* __restrict__ twg){
  __shared__ float2 Hs[HSLICE];            // 38.4 KB
  int x1 = blockIdx.x;
  int t = threadIdx.x;                     // 320
  const float* Hf = (const float*)(H + (size_t)x1*HSLICE);
  float* Hsf = (float*)Hs;
  for (int i = t; i < HSLICE*2; i += 320) Hsf[i] = Hf[i];
  __syncthreads();
  int grp = t / 160, r = t % 160;
  for (int i = 0; i < 64; i++){
    int x2 = 2*i + grp;
    float Er=0.f, Ei=0.f, Or=0.f, Oi=0.f;
    #pragma unroll
    for (int k2=0; k2<NK2; k2++){
      float2 a = Hs[k2*160 + r];
      float2 tw = twg[k2*S2 + x2];
      if (k2 & 1) cmac_inv(Or, Oi, a, tw);
      else        cmac_inv(Er, Ei, a, tw);
    }
    size_t b = ((size_t)(x1*S2) + x2)*GPEN + r;
    G[b]                      = __floats2half2_rn(Er+Or, Ei+Oi);
    G[b + (size_t)128*GPEN]   = __floats2half2_rn(Er-Or, Ei-Oi);
  }
}

extern "C" void kernel_launch(void* const* d_in, const int* in_sizes, int n_in,
                              void* d_out, int out_size, void* d_ws, size_t ws_size,
                              hipStream_t stream){
  const float* x  = (const float*)d_in[0];
  const float* sw = (const float*)d_in[1];
  const float* sb = (const float*)d_in[2];
  const float* Rr[4] = {(const float*)d_in[3],(const float*)d_in[6],(const float*)d_in[9],(const float*)d_in[12]};
  const float* Ri[4] = {(const float*)d_in[4],(const float*)d_in[7],(const float*)d_in[10],(const float*)d_in[13]};
  const float* w[4]  = {(const float*)d_in[5],(const float*)d_in[8],(const float*)d_in[11],(const float*)d_in[14]};
  const float* pw = (const float*)d_in[15];
  const float* pb = (const float*)d_in[16];
  float* out = (float*)d_out;
  float* ws = (float*)d_ws;

  __half*  v    = (__half*)(ws + OFF_V);
  __half2* g    = (__half2*)(ws + OFF_G);
  float2* h     = (float2*)(ws + OFF_H);
  float2* f     = (float2*)(ws + OFF_F);
  float2* Rf    = (float2*)(ws + OFF_RF);
  float2* tw128 = (float2*)(ws + OFF_TW128);
  float2* tw256 = (float2*)(ws + OFF_TW256);

  k_twiddles<<<35, 256, 0, stream>>>(tw128, tw256);
  k_shallow<<<NPEN/PB, 256, 0, stream>>>(x, sw, sb, v, g, tw128);
  for (int L = 0; L < 4; L++){
    k_stageB <<<dim3(S1,2), 256, 0, stream>>>(g, h, tw256);
    k_stageC <<<(NK1*HSLICE + 255)/256, 256, 0, stream>>>(h, f, tw256);
    k_mix    <<<(NK1*HSLICE + 255)/256, 256, 0, stream>>>(f, Rr[L], Ri[L], Rf);
    k_stageCi<<<(128*HSLICE)/256, 256, 0, stream>>>(Rf, h, tw256);
    k_stageBi<<<S1, 320, 0, stream>>>(h, g, tw256);
    if (L < 3)
      k_combine<<<NPEN/PB, 256, 0, stream>>>(v, g, w[L], tw128);
    else
      k_final<<<NPEN/PB, 256, 0, stream>>>(v, g, w[L], pw, pb, out, tw128);
  }
}

// Round 7
// 2947.478 us; speedup vs baseline: 2.4047x; 2.4047x over previous
//
#include <hip/hip_runtime.h>
#include <hip/hip_fp16.h>
#include <math.h>

// Problem constants
#define S1 256
#define S2 256
#define S3 128
#define DV 8
#define NK1 30
#define NK2 30
#define NK3 20
#define NPEN (S1*S2)          // 65536 pencils along x3
#define PENC (S3*DV)          // 1024 elements per v pencil (fp16)
#define GPEN (DV*NK3)         // 160 complex per g pencil (fp16 complex)
#define HSLICE (NK2*DV*NK3)   // 4800 complex per x1 slice of h (fp32)
#define PB 4                  // pencils per block in combine/shallow/final

// vnf LDS layout: [PB][DV][VNF_D] floats, parity plane at par*VNF_P
#define VNF_D 148
#define VNF_P 72

// Workspace layout in float-slots (4 bytes each) — total ~179.7 MiB
#define OFF_V     0ull
#define SZ_V      ((unsigned long long)NPEN*PENC/2)
#define OFF_G     (OFF_V + SZ_V)
#define SZ_G      ((unsigned long long)NPEN*GPEN)
#define OFF_H     (OFF_G + SZ_G)
#define SZ_H      ((unsigned long long)S1*HSLICE*2)
#define OFF_F     (OFF_H + SZ_H)
#define SZ_F      ((unsigned long long)NK1*HSLICE*2)
#define OFF_RF    (OFF_F + SZ_F)
#define OFF_TW128 (OFF_RF + SZ_F)
#define SZ_TW128  (2ull*NK3*64)
#define OFF_TW256 (OFF_TW128 + SZ_TW128)

__device__ __forceinline__ float gelu_f(float x){
  return 0.5f*x*(1.0f+erff(x*0.70710678118654752440f));
}
__device__ __forceinline__ void cmac_fwd(float& ar, float& ai, float2 a, float2 t){
  ar = fmaf(a.x, t.x, ar); ar = fmaf(-a.y, t.y, ar);
  ai = fmaf(a.x, t.y, ai); ai = fmaf(a.y, t.x, ai);
}
__device__ __forceinline__ void cmac_inv(float& ar, float& ai, float2 a, float2 t){
  ar = fmaf(a.x, t.x, ar); ar = fmaf(a.y, t.y, ar);
  ai = fmaf(a.y, t.x, ai); ai = fmaf(-a.x, t.y, ai);
}
// exchange an 8-byte packet with lane l^32 (full 64-lane wave)
__device__ __forceinline__ uint2 xor32_u2(uint2 a){
  uint2 r;
  r.x = (unsigned)__shfl_xor((int)a.x, 32);
  r.y = (unsigned)__shfl_xor((int)a.y, 32);
  return r;
}

// ---------------------------------------------------------------- twiddles
// tw128: [20][64] e^{-2pi i k x/128}, x<64 ; tw256: [30][256]
__global__ __launch_bounds__(256) void k_twiddles(float2* __restrict__ tw128,
                                                  float2* __restrict__ tw256){
  int idx = blockIdx.x*256 + threadIdx.x;
  if (idx < NK3*64){
    int k = idx >> 6, x = idx & 63;
    int m = (k*x) & 127;
    float a = -(float)m * (1.0f/64.0f);
    float s, c; sincospif(a, &s, &c);
    tw128[idx] = make_float2(c, s);   // (cos, -sin)
  }
  int j = idx - NK3*64;
  if (j >= 0 && j < NK2*S2){
    int k = j >> 8, x = j & 255;
    int m = (k*x) & 255;
    float a = -(float)m * (1.0f/128.0f);
    float s, c; sincospif(a, &s, &c);
    tw256[j] = make_float2(c, s);
  }
}

// =========================================================================
// fwd axis-2 DFT from folded vnf -> g, lanes 0..39 of each warp
// X[k3] = sum_{x<64} w_par[x] e^{-2pi i k3 x/128},  par = k3&1
// =========================================================================
__device__ __forceinline__ void fwd_dft_phase(const float (*vnfp)[VNF_D],
    const float2* tws, __half2* gout_pen, int l){
  if (l >= 40) return;
  int k3 = l % 20, dg = l / 20, par = k3 & 1;
  float ar[4] = {0,0,0,0}, ai[4] = {0,0,0,0};
  for (int x0 = 0; x0 < 64; x0 += 4){
    float4 vv[4];
    #pragma unroll
    for (int di=0; di<4; di++)
      vv[di] = *reinterpret_cast<const float4*>(&vnfp[dg*4+di][par*VNF_P + x0]);
    float2 t2[4];
    #pragma unroll
    for (int xi=0; xi<4; xi++) t2[xi] = tws[k3*67 + x0 + xi];
    #pragma unroll
    for (int di=0; di<4; di++){
      ar[di] = fmaf(vv[di].x, t2[0].x, ar[di]); ai[di] = fmaf(vv[di].x, t2[0].y, ai[di]);
      ar[di] = fmaf(vv[di].y, t2[1].x, ar[di]); ai[di] = fmaf(vv[di].y, t2[1].y, ai[di]);
      ar[di] = fmaf(vv[di].z, t2[2].x, ar[di]); ai[di] = fmaf(vv[di].z, t2[2].y, ai[di]);
      ar[di] = fmaf(vv[di].w, t2[3].x, ar[di]); ai[di] = fmaf(vv[di].w, t2[3].y, ai[di]);
    }
  }
  #pragma unroll
  for (int di=0; di<4; di++)
    gout_pen[(dg*4+di)*NK3 + k3] = __floats2half2_rn(ar[di], ai[di]);
}

// store v: lane l packs its 8B (e0 half) per q, swaps with lane l^32, and
// lanes<32 write q=0,1 / lanes>=32 write q=2,3 as full 16B contiguous chunks
__device__ __forceinline__ void store_v_swap(const float val[4][4],
    __half* vpen, int l, int xb){
  uint2 pk[4], ot[4];
  #pragma unroll
  for (int q=0; q<4; q++){
    union { uint2 u2; __half2 h2[2]; } u;
    u.h2[0] = __floats2half2_rn(val[q][0], val[q][1]);
    u.h2[1] = __floats2half2_rn(val[q][2], val[q][3]);
    pk[q] = u.u2;
  }
  #pragma unroll
  for (int q=0; q<4; q++) ot[q] = xor32_u2(pk[q]);
  int hi = l >> 5;
  #pragma unroll
  for (int qq=0; qq<2; qq++){
    int q = qq + hi*2;
    int x3 = xb + 32*q;
    uint4 full = hi ? make_uint4(ot[q].x, ot[q].y, pk[q].x, pk[q].y)
                    : make_uint4(pk[q].x, pk[q].y, ot[q].x, ot[q].y);
    *reinterpret_cast<uint4*>(vpen + x3*DV) = full;
  }
}

// ------------------------------------------------- shallow lift + axis-2 DFT
__global__ __launch_bounds__(256,2) void k_shallow(const float* __restrict__ x,
    const float* __restrict__ sw, const float* __restrict__ sb,
    __half* __restrict__ v, __half2* __restrict__ g,
    const float2* __restrict__ twg){
  __shared__ float2 tws[NK3*67];
  __shared__ float  vnf[PB][DV][VNF_D];
  int t = threadIdx.x;
  size_t pen_base = (size_t)blockIdx.x * PB;
  for (int i=t; i<NK3*64; i+=256){ int k=i>>6, xx=i&63; tws[k*67+xx] = twg[i]; }
  int p = t >> 6, l = t & 63;
  int xb = l & 31, e0 = (l >> 5)*4;
  size_t pen = pen_base + p;
  float swr[4], sbr[4];
  #pragma unroll
  for (int j=0;j<4;j++){ swr[j] = sw[e0+j]; sbr[j] = sb[e0+j]; }
  float val[4][4];
  #pragma unroll
  for (int q=0; q<4; q++){
    int x3 = xb + 32*q;
    float xv = x[(pen<<7) + x3];
    #pragma unroll
    for (int j=0;j<4;j++) val[q][j] = gelu_f(fmaf(xv, swr[j], sbr[j]));
  }
  store_v_swap(val, v + (pen<<10), l, xb);
  #pragma unroll
  for (int j=0;j<4;j++){
    vnf[p][e0+j][xb]             = val[0][j] + val[2][j];
    vnf[p][e0+j][VNF_P + xb]     = val[0][j] - val[2][j];
    vnf[p][e0+j][xb+32]          = val[1][j] + val[3][j];
    vnf[p][e0+j][VNF_P + xb+32]  = val[1][j] - val[3][j];
  }
  __syncthreads();
  fwd_dft_phase(vnf[p], tws, g + pen*GPEN, l);
}

// --------------------- combine: inv axis-2 DFT + skip + GELU + next fwd DFT
__global__ __launch_bounds__(256,2) void k_combine(__half* __restrict__ v,
    __half2* __restrict__ g, const float* __restrict__ w,
    const float2* __restrict__ twg){
  __shared__ float2 tws[NK3*67];
  __shared__ float  vnf[PB][DV][VNF_D];
  __shared__ float2 Gsm[PB][GPEN];
  __shared__ float  wsm[64];
  int t = threadIdx.x;
  size_t pen_base = (size_t)blockIdx.x * PB;
  for (int i=t; i<NK3*64; i+=256){ int k=i>>6, xx=i&63; tws[k*67+xx] = twg[i]; }
  {
    const __half2* gsrc = g + pen_base*GPEN;
    float2* Gf = &Gsm[0][0];
    for (int i=t; i<PB*GPEN; i+=256){
      float2 gv = __half22float2(gsrc[i]);
      if (i % 20){ gv.x *= 2.0f; gv.y *= 2.0f; }   // irfft factor 2, k3>0
      Gf[i] = gv;
    }
  }
  if (t < 64) wsm[t] = w[t];
  __syncthreads();

  int p = t >> 6, l = t & 63;
  int xb = l & 31, e0 = (l >> 5)*4;
  size_t pen = pen_base + p;
  float wr[DV][4];
  #pragma unroll
  for (int d=0; d<DV; d++)
    #pragma unroll
    for (int j=0; j<4; j++) wr[d][j] = wsm[d*DV + e0 + j];

  // inverse axis-2 with parity fold: E = even k3 (incl DC), O = odd k3
  float E[2][4], O[2][4];
  #pragma unroll
  for (int xi=0; xi<2; xi++)
    #pragma unroll
    for (int j=0; j<4; j++){ E[xi][j] = Gsm[p][(e0+j)*NK3].x; O[xi][j] = 0.f; }
  #pragma unroll
  for (int k3=1; k3<NK3; k3++){
    float2 c0 = tws[k3*67 + xb];
    float2 c1 = tws[k3*67 + xb + 32];
    float2 gq[4];
    #pragma unroll
    for (int j=0; j<4; j++) gq[j] = Gsm[p][(e0+j)*NK3 + k3];
    if (k3 & 1){
      #pragma unroll
      for (int j=0; j<4; j++){
        O[0][j] = fmaf(gq[j].x, c0.x, O[0][j]); O[0][j] = fmaf(gq[j].y, c0.y, O[0][j]);
        O[1][j] = fmaf(gq[j].x, c1.x, O[1][j]); O[1][j] = fmaf(gq[j].y, c1.y, O[1][j]);
      }
    } else {
      #pragma unroll
      for (int j=0; j<4; j++){
        E[0][j] = fmaf(gq[j].x, c0.x, E[0][j]); E[0][j] = fmaf(gq[j].y, c0.y, E[0][j]);
        E[1][j] = fmaf(gq[j].x, c1.x, E[1][j]); E[1][j] = fmaf(gq[j].y, c1.y, E[1][j]);
      }
    }
  }
  // skip + gelu ; q: x3 = xb+32q
  float val[4][4];
  #pragma unroll
  for (int q=0; q<4; q++){
    int x3 = xb + 32*q;
    union { uint4 u4; __half2 h2[4]; } lk;
    lk.u4 = *reinterpret_cast<const uint4*>(v + (pen<<10) + x3*DV);
    float vv[8];
    #pragma unroll
    for (int qq=0; qq<4; qq++){
      float2 f2 = __half22float2(lk.h2[qq]);
      vv[2*qq] = f2.x; vv[2*qq+1] = f2.y;
    }
    float s[4];
    #pragma unroll
    for (int j=0; j<4; j++){
      float e = E[q&1][j], o = O[q&1][j];
      s[j] = (q < 2) ? (e + o) : (e - o);
    }
    #pragma unroll
    for (int d=0; d<DV; d++)
      #pragma unroll
      for (int j=0; j<4; j++) s[j] = fmaf(vv[d], wr[d][j], s[j]);
    #pragma unroll
    for (int j=0; j<4; j++) val[q][j] = gelu_f(s[j]);
  }
  store_v_swap(val, v + (pen<<10), l, xb);
  // post-gelu parity fold for next fwd DFT
  #pragma unroll
  for (int j=0; j<4; j++){
    vnf[p][e0+j][xb]            = val[0][j] + val[2][j];
    vnf[p][e0+j][VNF_P + xb]    = val[0][j] - val[2][j];
    vnf[p][e0+j][xb+32]         = val[1][j] + val[3][j];
    vnf[p][e0+j][VNF_P + xb+32] = val[1][j] - val[3][j];
  }
  __syncthreads();
  fwd_dft_phase(vnf[p], tws, g + pen*GPEN, l);
}

// --------------------- final: inv axis-2 DFT + skip + GELU + projection
__global__ __launch_bounds__(256,2) void k_final(const __half* __restrict__ v,
    const __half2* __restrict__ g, const float* __restrict__ w,
    const float* __restrict__ pw, const float* __restrict__ pb,
    float* __restrict__ out, const float2* __restrict__ twg){
  __shared__ float2 tws[NK3*67];
  __shared__ float  vnr[PB][DV][128];
  __shared__ float2 Gsm[PB][GPEN];
  __shared__ float  wsm[64];
  __shared__ float  pws[DV];
  __shared__ float  pbs;
  int t = threadIdx.x;
  size_t pen_base = (size_t)blockIdx.x * PB;
  for (int i=t; i<NK3*64; i+=256){ int k=i>>6, xx=i&63; tws[k*67+xx] = twg[i]; }
  {
    const __half2* gsrc = g + pen_base*GPEN;
    float2* Gf = &Gsm[0][0];
    for (int i=t; i<PB*GPEN; i+=256){
      float2 gv = __half22float2(gsrc[i]);
      if (i % 20){ gv.x *= 2.0f; gv.y *= 2.0f; }
      Gf[i] = gv;
    }
  }
  if (t < 64) wsm[t] = w[t];
  else if (t < 64+DV) pws[t-64] = pw[t-64];
  else if (t == 64+DV) pbs = pb[0];
  __syncthreads();

  int p = t >> 6, l = t & 63;
  int xb = l & 31, e0 = (l >> 5)*4;
  size_t pen = pen_base + p;
  float wr[DV][4];
  #pragma unroll
  for (int d=0; d<DV; d++)
    #pragma unroll
    for (int j=0; j<4; j++) wr[d][j] = wsm[d*DV + e0 + j];

  float E[2][4], O[2][4];
  #pragma unroll
  for (int xi=0; xi<2; xi++)
    #pragma unroll
    for (int j=0; j<4; j++){ E[xi][j] = Gsm[p][(e0+j)*NK3].x; O[xi][j] = 0.f; }
  #pragma unroll
  for (int k3=1; k3<NK3; k3++){
    float2 c0 = tws[k3*67 + xb];
    float2 c1 = tws[k3*67 + xb + 32];
    float2 gq[4];
    #pragma unroll
    for (int j=0; j<4; j++) gq[j] = Gsm[p][(e0+j)*NK3 + k3];
    if (k3 & 1){
      #pragma unroll
      for (int j=0; j<4; j++){
        O[0][j] = fmaf(gq[j].x, c0.x, O[0][j]); O[0][j] = fmaf(gq[j].y, c0.y, O[0][j]);
        O[1][j] = fmaf(gq[j].x, c1.x, O[1][j]); O[1][j] = fmaf(gq[j].y, c1.y, O[1][j]);
      }
    } else {
      #pragma unroll
      for (int j=0; j<4; j++){
        E[0][j] = fmaf(gq[j].x, c0.x, E[0][j]); E[0][j] = fmaf(gq[j].y, c0.y, E[0][j]);
        E[1][j] = fmaf(gq[j].x, c1.x, E[1][j]); E[1][j] = fmaf(gq[j].y, c1.y, E[1][j]);
      }
    }
  }
  #pragma unroll
  for (int q=0; q<4; q++){
    int x3 = xb + 32*q;
    union { uint4 u4; __half2 h2[4]; } lk;
    lk.u4 = *reinterpret_cast<const uint4*>(v + (pen<<10) + x3*DV);
    float vv[8];
    #pragma unroll
    for (int qq=0; qq<4; qq++){
      float2 f2 = __half22float2(lk.h2[qq]);
      vv[2*qq] = f2.x; vv[2*qq+1] = f2.y;
    }
    float s[4];
    #pragma unroll
    for (int j=0; j<4; j++){
      float e = E[q&1][j], o = O[q&1][j];
      s[j] = (q < 2) ? (e + o) : (e - o);
    }
    #pragma unroll
    for (int d=0; d<DV; d++)
      #pragma unroll
      for (int j=0; j<4; j++) s[j] = fmaf(vv[d], wr[d][j], s[j]);
    #pragma unroll
    for (int j=0; j<4; j++) vnr[p][e0+j][x3] = gelu_f(s[j]);
  }
  __syncthreads();
  float pwr[DV];
  #pragma unroll
  for (int e=0; e<DV; e++) pwr[e] = pws[e];
  float pbv = pbs;
  #pragma unroll
  for (int it=0; it<2; it++){
    int p2 = it*2 + (t>>7);
    int x3 = t & 127;
    float acc = pbv;
    #pragma unroll
    for (int e=0; e<DV; e++) acc = fmaf(vnr[p2][e][x3], pwr[e], acc);
    out[((pen_base + p2)<<7) + x3] = acc;
  }
}

// ------------------------------------------------------- axis-1 forward DFT
// grid (S1, 2); parity fold over x2 / x2+128 (chunk c / c+4)
__global__ __launch_bounds__(256) void k_stageB(const __half2* __restrict__ g,
    float2* __restrict__ h, const float2* __restrict__ twg){
  __shared__ unsigned int gsm[2][32*160];   // 40 KB
  int x1 = blockIdx.x;
  int k3o = blockIdx.y * 10;
  int t = threadIdx.x;
  int k2 = t >> 3, d = t & 7;
  float sgn = (k2 & 1) ? -1.0f : 1.0f;
  float ar[10], ai[10];
  #pragma unroll
  for (int j=0;j<10;j++){ ar[j]=0.f; ai[j]=0.f; }
  for (int c = 0; c < 4; c++){
    __syncthreads();
    const uint4* s0 = reinterpret_cast<const uint4*>(g + (size_t)(x1*S2 + c*32)*GPEN);
    const uint4* s1 = reinterpret_cast<const uint4*>(g + (size_t)(x1*S2 + (c+4)*32)*GPEN);
    uint4* d0 = reinterpret_cast<uint4*>(gsm[0]);
    uint4* d1 = reinterpret_cast<uint4*>(gsm[1]);
    #pragma unroll
    for (int r=0; r<5; r++){ d0[r*256 + t] = s0[r*256 + t]; d1[r*256 + t] = s1[r*256 + t]; }
    __syncthreads();
    if (t < 240){
      for (int x2l = 0; x2l < 32; x2l++){
        float2 tw = twg[k2*S2 + c*32 + x2l];
        const uint2* qlo = reinterpret_cast<const uint2*>(&gsm[0][x2l*160 + d*20 + k3o]);
        const uint2* qhi = reinterpret_cast<const uint2*>(&gsm[1][x2l*160 + d*20 + k3o]);
        #pragma unroll
        for (int jj=0; jj<5; jj++){
          uint2 ulo = qlo[jj], uhi = qhi[jj];
          float2 a0 = __half22float2(*reinterpret_cast<const __half2*>(&ulo.x));
          float2 b0 = __half22float2(*reinterpret_cast<const __half2*>(&uhi.x));
          float2 a1 = __half22float2(*reinterpret_cast<const __half2*>(&ulo.y));
          float2 b1 = __half22float2(*reinterpret_cast<const __half2*>(&uhi.y));
          float2 g0 = make_float2(fmaf(sgn, b0.x, a0.x), fmaf(sgn, b0.y, a0.y));
          float2 g1 = make_float2(fmaf(sgn, b1.x, a1.x), fmaf(sgn, b1.y, a1.y));
          cmac_fwd(ar[2*jj],   ai[2*jj],   g0, tw);
          cmac_fwd(ar[2*jj+1], ai[2*jj+1], g1, tw);
        }
      }
    }
  }
  if (t < 240){
    float2* hp = h + (size_t)((x1*NK2 + k2)*(DV*NK3) + d*NK3 + k3o);
    #pragma unroll
    for (int j=0;j<10;j++) hp[j] = make_float2(ar[j], ai[j]);
  }
}

// ------------------------------------------------------- axis-0 forward DFT
// parity fold over x1 / x1+128
__global__ __launch_bounds__(256) void k_stageC(const float2* __restrict__ h,
    float2* __restrict__ f, const float2* __restrict__ tw256){
  int idx = blockIdx.x*256 + threadIdx.x;
  if (idx >= NK1*HSLICE) return;
  int k1 = idx / HSLICE, r = idx % HSLICE;
  float sgn = (k1 & 1) ? -1.0f : 1.0f;
  float ar=0.f, ai=0.f;
  const float2* twp = &tw256[k1*S1];
  for (int x1=0; x1<128; x1++){
    float2 h1 = h[(size_t)x1*HSLICE + r];
    float2 h2 = h[(size_t)(x1+128)*HSLICE + r];
    float2 hv = make_float2(fmaf(sgn, h2.x, h1.x), fmaf(sgn, h2.y, h1.y));
    cmac_fwd(ar, ai, hv, twp[x1]);
  }
  f[idx] = make_float2(ar, ai);
}

// ------------------------------------------------------------- mode mixing
__global__ __launch_bounds__(256) void k_mix(const float2* __restrict__ f,
    const float* __restrict__ Rr, const float* __restrict__ Ri,
    float2* __restrict__ Rf){
  int idx = blockIdx.x*256 + threadIdx.x;
  if (idx >= NK1*HSLICE) return;
  int k12 = idx / (DV*NK3), r = idx % (DV*NK3);
  int e = r / NK3, k3 = r % NK3;
  const float2* fp  = &f[(size_t)k12*(DV*NK3) + k3];
  const float* rrp = &Rr[((size_t)k12*NK3 + k3)*64 + e];
  const float* rip = &Ri[((size_t)k12*NK3 + k3)*64 + e];
  float ar=0.f, ai=0.f;
  #pragma unroll
  for (int d=0; d<DV; d++){
    float2 fv = fp[d*NK3];
    float wr = rrp[d*DV], wi = rip[d*DV];
    ar = fmaf(fv.x, wr, ar); ar = fmaf(-fv.y, wi, ar);
    ai = fmaf(fv.x, wi, ai); ai = fmaf(fv.y, wr, ai);
  }
  const float sc = 1.1920928955078125e-7f; // 1/(256*256*128)
  Rf[idx] = make_float2(ar*sc, ai*sc);
}

// ------------------------------------------------------- axis-0 inverse DFT
// parity fold: one thread emits H[x1] and H[x1+128]
__global__ __launch_bounds__(256) void k_stageCi(const float2* __restrict__ Rf,
    float2* __restrict__ H, const float2* __restrict__ tw256){
  int idx = blockIdx.x*256 + threadIdx.x;   // exactly 128*4800 threads
  int x1 = idx / HSLICE, r = idx % HSLICE;
  float Er=0.f, Ei=0.f, Or=0.f, Oi=0.f;
  #pragma unroll
  for (int k1=0; k1<NK1; k1++){
    float2 a = Rf[(size_t)k1*HSLICE + r];
    float2 tw = tw256[k1*S1 + x1];
    if (k1 & 1) cmac_inv(Or, Oi, a, tw);
    else        cmac_inv(Er, Ei, a, tw);
  }
  H[(size_t)x1*HSLICE + r]        = make_float2(Er+Or, Ei+Oi);
  H[(size_t)(x1+128)*HSLICE + r]  = make_float2(Er-Or, Ei-Oi);
}

// ------------------------------------------------------- axis-1 inverse DFT
// parity fold: one thread-iter emits G[x2] and G[x2+128]
__global__ __launch_bounds__(320) void k_stageBi(const float2* __restrict__ H,
    __half2* __restrict__ G, const float2* __restrict__ twg){
  __shared__ float2 Hs[HSLICE];            // 38.4 KB
  int x1 = blockIdx.x;
  int t = threadIdx.x;                     // 320
  const float* Hf = (const float*)(H + (size_t)x1*HSLICE);
  float* Hsf = (float*)Hs;
  for (int i = t; i < HSLICE*2; i += 320) Hsf[i] = Hf[i];
  __syncthreads();
  int grp = t / 160, r = t % 160;
  for (int i = 0; i < 64; i++){
    int x2 = 2*i + grp;
    float Er=0.f, Ei=0.f, Or=0.f, Oi=0.f;
    #pragma unroll
    for (int k2=0; k2<NK2; k2++){
      float2 a = Hs[k2*160 + r];
      float2 tw = twg[k2*S2 + x2];
      if (k2 & 1) cmac_inv(Or, Oi, a, tw);
      else        cmac_inv(Er, Ei, a, tw);
    }
    size_t b = ((size_t)(x1*S2) + x2)*GPEN + r;
    G[b]                      = __floats2half2_rn(Er+Or, Ei+Oi);
    G[b + (size_t)128*GPEN]   = __floats2half2_rn(Er-Or, Ei-Oi);
  }
}

extern "C" void kernel_launch(void* const* d_in, const int* in_sizes, int n_in,
                              void* d_out, int out_size, void* d_ws, size_t ws_size,
                              hipStream_t stream){
  const float* x  = (const float*)d_in[0];
  const float* sw = (const float*)d_in[1];
  const float* sb = (const float*)d_in[2];
  const float* Rr[4] = {(const float*)d_in[3],(const float*)d_in[6],(const float*)d_in[9],(const float*)d_in[12]};
  const float* Ri[4] = {(const float*)d_in[4],(const float*)d_in[7],(const float*)d_in[10],(const float*)d_in[13]};
  const float* w[4]  = {(const float*)d_in[5],(const float*)d_in[8],(const float*)d_in[11],(const float*)d_in[14]};
  const float* pw = (const float*)d_in[15];
  const float* pb = (const float*)d_in[16];
  float* out = (float*)d_out;
  float* ws = (float*)d_ws;

  __half*  v    = (__half*)(ws + OFF_V);
  __half2* g    = (__half2*)(ws + OFF_G);
  float2* h     = (float2*)(ws + OFF_H);
  float2* f     = (float2*)(ws + OFF_F);
  float2* Rf    = (float2*)(ws + OFF_RF);
  float2* tw128 = (float2*)(ws + OFF_TW128);
  float2* tw256 = (float2*)(ws + OFF_TW256);

  k_twiddles<<<35, 256, 0, stream>>>(tw128, tw256);
  k_shallow<<<NPEN/PB, 256, 0, stream>>>(x, sw, sb, v, g, tw128);
  for (int L = 0; L < 4; L++){
    k_stageB <<<dim3(S1,2), 256, 0, stream>>>(g, h, tw256);
    k_stageC <<<(NK1*HSLICE + 255)/256, 256, 0, stream>>>(h, f, tw256);
    k_mix    <<<(NK1*HSLICE + 255)/256, 256, 0, stream>>>(f, Rr[L], Ri[L], Rf);
    k_stageCi<<<(128*HSLICE)/256, 256, 0, stream>>>(Rf, h, tw256);
    k_stageBi<<<S1, 320, 0, stream>>>(h, g, tw256);
    if (L < 3)
      k_combine<<<NPEN/PB, 256, 0, stream>>>(v, g, w[L], tw128);
    else
      k_final<<<NPEN/PB, 256, 0, stream>>>(v, g, w[L], pw, pb, out, tw128);
  }
}

// Round 8
// 2859.630 us; speedup vs baseline: 2.4786x; 1.0307x over previous
//
#include <hip/hip_runtime.h>
#include <hip/hip_fp16.h>
#include <math.h>

// Problem constants
#define S1 256
#define S2 256
#define S3 128
#define DV 8
#define NK1 30
#define NK2 30
#define NK3 20
#define NPEN (S1*S2)          // 65536 pencils along x3
#define PENC (S3*DV)          // 1024 elements per v pencil (fp16)
#define GPEN (DV*NK3)         // 160 complex per g pencil (fp16 complex)
#define HSLICE (NK2*DV*NK3)   // 4800 complex per x1 slice of h (fp32)
#define PB 4                  // pencils per block in combine/shallow/final

// vnf LDS layout: [PB][DV][VNF_D] floats, parity plane at par*VNF_P
#define VNF_D 148
#define VNF_P 72

// Workspace layout in float-slots (4 bytes each) — total ~179.7 MiB
#define OFF_V     0ull
#define SZ_V      ((unsigned long long)NPEN*PENC/2)
#define OFF_G     (OFF_V + SZ_V)
#define SZ_G      ((unsigned long long)NPEN*GPEN)
#define OFF_H     (OFF_G + SZ_G)
#define SZ_H      ((unsigned long long)S1*HSLICE*2)
#define OFF_F     (OFF_H + SZ_H)
#define SZ_F      ((unsigned long long)NK1*HSLICE*2)
#define OFF_RF    (OFF_F + SZ_F)
#define OFF_TW128 (OFF_RF + SZ_F)
#define SZ_TW128  (2ull*NK3*64)
#define OFF_TW256 (OFF_TW128 + SZ_TW128)

__device__ __forceinline__ float gelu_f(float x){
  return 0.5f*x*(1.0f+erff(x*0.70710678118654752440f));
}
__device__ __forceinline__ void cmac_fwd(float& ar, float& ai, float2 a, float2 t){
  ar = fmaf(a.x, t.x, ar); ar = fmaf(-a.y, t.y, ar);
  ai = fmaf(a.x, t.y, ai); ai = fmaf(a.y, t.x, ai);
}
__device__ __forceinline__ void cmac_inv(float& ar, float& ai, float2 a, float2 t){
  ar = fmaf(a.x, t.x, ar); ar = fmaf(a.y, t.y, ar);
  ai = fmaf(a.y, t.x, ai); ai = fmaf(-a.x, t.y, ai);
}
// exchange an 8-byte packet with lane l^32 (full 64-lane wave)
__device__ __forceinline__ uint2 xor32_u2(uint2 a){
  uint2 r;
  r.x = (unsigned)__shfl_xor((int)a.x, 32);
  r.y = (unsigned)__shfl_xor((int)a.y, 32);
  return r;
}
__device__ __forceinline__ uint2 pack_h4(const float v0, const float v1,
                                         const float v2, const float v3){
  union { uint2 u2; __half2 h2[2]; } u;
  u.h2[0] = __floats2half2_rn(v0, v1);
  u.h2[1] = __floats2half2_rn(v2, v3);
  return u.u2;
}

// ---------------------------------------------------------------- twiddles
// tw128: [20][64] e^{-2pi i k x/128}, x<64 ; tw256: [30][256]
__global__ __launch_bounds__(256) void k_twiddles(float2* __restrict__ tw128,
                                                  float2* __restrict__ tw256){
  int idx = blockIdx.x*256 + threadIdx.x;
  if (idx < NK3*64){
    int k = idx >> 6, x = idx & 63;
    int m = (k*x) & 127;
    float a = -(float)m * (1.0f/64.0f);
    float s, c; sincospif(a, &s, &c);
    tw128[idx] = make_float2(c, s);   // (cos, -sin)
  }
  int j = idx - NK3*64;
  if (j >= 0 && j < NK2*S2){
    int k = j >> 8, x = j & 255;
    int m = (k*x) & 255;
    float a = -(float)m * (1.0f/128.0f);
    float s, c; sincospif(a, &s, &c);
    tw256[j] = make_float2(c, s);
  }
}

// =========================================================================
// fwd axis-2 DFT from folded vnf -> g, lanes 0..39 of each warp
// X[k3] = sum_{x<64} w_par[x] e^{-2pi i k3 x/128},  par = k3&1
// =========================================================================
__device__ __forceinline__ void fwd_dft_phase(const float (*vnfp)[VNF_D],
    const float2* tws, __half2* gout_pen, int l){
  if (l >= 40) return;
  int k3 = l % 20, dg = l / 20, par = k3 & 1;
  float ar[4] = {0,0,0,0}, ai[4] = {0,0,0,0};
  for (int x0 = 0; x0 < 64; x0 += 4){
    float4 vv[4];
    #pragma unroll
    for (int di=0; di<4; di++)
      vv[di] = *reinterpret_cast<const float4*>(&vnfp[dg*4+di][par*VNF_P + x0]);
    float2 t2[4];
    #pragma unroll
    for (int xi=0; xi<4; xi++) t2[xi] = tws[k3*67 + x0 + xi];
    #pragma unroll
    for (int di=0; di<4; di++){
      ar[di] = fmaf(vv[di].x, t2[0].x, ar[di]); ai[di] = fmaf(vv[di].x, t2[0].y, ai[di]);
      ar[di] = fmaf(vv[di].y, t2[1].x, ar[di]); ai[di] = fmaf(vv[di].y, t2[1].y, ai[di]);
      ar[di] = fmaf(vv[di].z, t2[2].x, ar[di]); ai[di] = fmaf(vv[di].z, t2[2].y, ai[di]);
      ar[di] = fmaf(vv[di].w, t2[3].x, ar[di]); ai[di] = fmaf(vv[di].w, t2[3].y, ai[di]);
    }
  }
  #pragma unroll
  for (int di=0; di<4; di++)
    gout_pen[(dg*4+di)*NK3 + k3] = __floats2half2_rn(ar[di], ai[di]);
}

// store v: lane l packs its 8B (e0 half) per q, swaps with lane l^32;
// lanes<32 write q=0,1 / lanes>=32 write q=2,3 as full 16B contiguous chunks.
// NO runtime-indexed arrays (rule #20): named scalars + cndmask selects.
__device__ __forceinline__ void store_v_swap(const float val[4][4],
    __half* vpen, int l, int xb){
  uint2 pk0 = pack_h4(val[0][0], val[0][1], val[0][2], val[0][3]);
  uint2 pk1 = pack_h4(val[1][0], val[1][1], val[1][2], val[1][3]);
  uint2 pk2 = pack_h4(val[2][0], val[2][1], val[2][2], val[2][3]);
  uint2 pk3 = pack_h4(val[3][0], val[3][1], val[3][2], val[3][3]);
  uint2 ot0 = xor32_u2(pk0);
  uint2 ot1 = xor32_u2(pk1);
  uint2 ot2 = xor32_u2(pk2);
  uint2 ot3 = xor32_u2(pk3);
  int hi = l >> 5;
  uint4 f0 = hi ? make_uint4(ot2.x, ot2.y, pk2.x, pk2.y)
                : make_uint4(pk0.x, pk0.y, ot0.x, ot0.y);
  uint4 f1 = hi ? make_uint4(ot3.x, ot3.y, pk3.x, pk3.y)
                : make_uint4(pk1.x, pk1.y, ot1.x, ot1.y);
  int x3a = xb + (hi ? 64 : 0);
  *reinterpret_cast<uint4*>(vpen + x3a*DV) = f0;
  *reinterpret_cast<uint4*>(vpen + (x3a+32)*DV) = f1;
}

// ------------------------------------------------- shallow lift + axis-2 DFT
__global__ __launch_bounds__(256) void k_shallow(const float* __restrict__ x,
    const float* __restrict__ sw, const float* __restrict__ sb,
    __half* __restrict__ v, __half2* __restrict__ g,
    const float2* __restrict__ twg){
  __shared__ float2 tws[NK3*67];
  __shared__ float  vnf[PB][DV][VNF_D];
  int t = threadIdx.x;
  size_t pen_base = (size_t)blockIdx.x * PB;
  for (int i=t; i<NK3*64; i+=256){ int k=i>>6, xx=i&63; tws[k*67+xx] = twg[i]; }
  int p = t >> 6, l = t & 63;
  int xb = l & 31, e0 = (l >> 5)*4;
  size_t pen = pen_base + p;
  float swr[4], sbr[4];
  #pragma unroll
  for (int j=0;j<4;j++){ swr[j] = sw[e0+j]; sbr[j] = sb[e0+j]; }
  float val[4][4];
  #pragma unroll
  for (int q=0; q<4; q++){
    int x3 = xb + 32*q;
    float xv = x[(pen<<7) + x3];
    #pragma unroll
    for (int j=0;j<4;j++) val[q][j] = gelu_f(fmaf(xv, swr[j], sbr[j]));
  }
  store_v_swap(val, v + (pen<<10), l, xb);
  #pragma unroll
  for (int j=0;j<4;j++){
    vnf[p][e0+j][xb]             = val[0][j] + val[2][j];
    vnf[p][e0+j][VNF_P + xb]     = val[0][j] - val[2][j];
    vnf[p][e0+j][xb+32]          = val[1][j] + val[3][j];
    vnf[p][e0+j][VNF_P + xb+32]  = val[1][j] - val[3][j];
  }
  __syncthreads();
  fwd_dft_phase(vnf[p], tws, g + pen*GPEN, l);
}

// --------------------- combine: inv axis-2 DFT + skip + GELU + next fwd DFT
__global__ __launch_bounds__(256) void k_combine(__half* __restrict__ v,
    __half2* __restrict__ g, const float* __restrict__ w,
    const float2* __restrict__ twg){
  __shared__ float2 tws[NK3*67];
  __shared__ float  vnf[PB][DV][VNF_D];
  __shared__ float2 Gsm[PB][GPEN];
  __shared__ float  wsm[64];
  int t = threadIdx.x;
  size_t pen_base = (size_t)blockIdx.x * PB;
  for (int i=t; i<NK3*64; i+=256){ int k=i>>6, xx=i&63; tws[k*67+xx] = twg[i]; }
  {
    const __half2* gsrc = g + pen_base*GPEN;
    float2* Gf = &Gsm[0][0];
    for (int i=t; i<PB*GPEN; i+=256){
      float2 gv = __half22float2(gsrc[i]);
      if (i % 20){ gv.x *= 2.0f; gv.y *= 2.0f; }   // irfft factor 2, k3>0
      Gf[i] = gv;
    }
  }
  if (t < 64) wsm[t] = w[t];
  __syncthreads();

  int p = t >> 6, l = t & 63;
  int xb = l & 31, e0 = (l >> 5)*4;
  size_t pen = pen_base + p;
  float wr[DV][4];
  #pragma unroll
  for (int d=0; d<DV; d++)
    #pragma unroll
    for (int j=0; j<4; j++) wr[d][j] = wsm[d*DV + e0 + j];

  // inverse axis-2 with parity fold: E = even k3 (incl DC), O = odd k3
  float E[2][4], O[2][4];
  #pragma unroll
  for (int xi=0; xi<2; xi++)
    #pragma unroll
    for (int j=0; j<4; j++){ E[xi][j] = Gsm[p][(e0+j)*NK3].x; O[xi][j] = 0.f; }
  #pragma unroll
  for (int k3=1; k3<NK3; k3++){
    float2 c0 = tws[k3*67 + xb];
    float2 c1 = tws[k3*67 + xb + 32];
    float2 gq[4];
    #pragma unroll
    for (int j=0; j<4; j++) gq[j] = Gsm[p][(e0+j)*NK3 + k3];
    if (k3 & 1){
      #pragma unroll
      for (int j=0; j<4; j++){
        O[0][j] = fmaf(gq[j].x, c0.x, O[0][j]); O[0][j] = fmaf(gq[j].y, c0.y, O[0][j]);
        O[1][j] = fmaf(gq[j].x, c1.x, O[1][j]); O[1][j] = fmaf(gq[j].y, c1.y, O[1][j]);
      }
    } else {
      #pragma unroll
      for (int j=0; j<4; j++){
        E[0][j] = fmaf(gq[j].x, c0.x, E[0][j]); E[0][j] = fmaf(gq[j].y, c0.y, E[0][j]);
        E[1][j] = fmaf(gq[j].x, c1.x, E[1][j]); E[1][j] = fmaf(gq[j].y, c1.y, E[1][j]);
      }
    }
  }
  // skip + gelu ; q: x3 = xb+32q
  float val[4][4];
  #pragma unroll
  for (int q=0; q<4; q++){
    int x3 = xb + 32*q;
    union { uint4 u4; __half2 h2[4]; } lk;
    lk.u4 = *reinterpret_cast<const uint4*>(v + (pen<<10) + x3*DV);
    float vv[8];
    #pragma unroll
    for (int qq=0; qq<4; qq++){
      float2 f2 = __half22float2(lk.h2[qq]);
      vv[2*qq] = f2.x; vv[2*qq+1] = f2.y;
    }
    float s[4];
    #pragma unroll
    for (int j=0; j<4; j++){
      float e = E[q&1][j], o = O[q&1][j];
      s[j] = (q < 2) ? (e + o) : (e - o);
    }
    #pragma unroll
    for (int d=0; d<DV; d++)
      #pragma unroll
      for (int j=0; j<4; j++) s[j] = fmaf(vv[d], wr[d][j], s[j]);
    #pragma unroll
    for (int j=0; j<4; j++) val[q][j] = gelu_f(s[j]);
  }
  store_v_swap(val, v + (pen<<10), l, xb);
  // post-gelu parity fold for next fwd DFT
  #pragma unroll
  for (int j=0; j<4; j++){
    vnf[p][e0+j][xb]            = val[0][j] + val[2][j];
    vnf[p][e0+j][VNF_P + xb]    = val[0][j] - val[2][j];
    vnf[p][e0+j][xb+32]         = val[1][j] + val[3][j];
    vnf[p][e0+j][VNF_P + xb+32] = val[1][j] - val[3][j];
  }
  __syncthreads();
  fwd_dft_phase(vnf[p], tws, g + pen*GPEN, l);
}

// --------------------- final: inv axis-2 DFT + skip + GELU + projection
__global__ __launch_bounds__(256) void k_final(const __half* __restrict__ v,
    const __half2* __restrict__ g, const float* __restrict__ w,
    const float* __restrict__ pw, const float* __restrict__ pb,
    float* __restrict__ out, const float2* __restrict__ twg){
  __shared__ float2 tws[NK3*67];
  __shared__ float  vnr[PB][DV][128];
  __shared__ float2 Gsm[PB][GPEN];
  __shared__ float  wsm[64];
  __shared__ float  pws[DV];
  __shared__ float  pbs;
  int t = threadIdx.x;
  size_t pen_base = (size_t)blockIdx.x * PB;
  for (int i=t; i<NK3*64; i+=256){ int k=i>>6, xx=i&63; tws[k*67+xx] = twg[i]; }
  {
    const __half2* gsrc = g + pen_base*GPEN;
    float2* Gf = &Gsm[0][0];
    for (int i=t; i<PB*GPEN; i+=256){
      float2 gv = __half22float2(gsrc[i]);
      if (i % 20){ gv.x *= 2.0f; gv.y *= 2.0f; }
      Gf[i] = gv;
    }
  }
  if (t < 64) wsm[t] = w[t];
  else if (t < 64+DV) pws[t-64] = pw[t-64];
  else if (t == 64+DV) pbs = pb[0];
  __syncthreads();

  int p = t >> 6, l = t & 63;
  int xb = l & 31, e0 = (l >> 5)*4;
  size_t pen = pen_base + p;
  float wr[DV][4];
  #pragma unroll
  for (int d=0; d<DV; d++)
    #pragma unroll
    for (int j=0; j<4; j++) wr[d][j] = wsm[d*DV + e0 + j];

  float E[2][4], O[2][4];
  #pragma unroll
  for (int xi=0; xi<2; xi++)
    #pragma unroll
    for (int j=0; j<4; j++){ E[xi][j] = Gsm[p][(e0+j)*NK3].x; O[xi][j] = 0.f; }
  #pragma unroll
  for (int k3=1; k3<NK3; k3++){
    float2 c0 = tws[k3*67 + xb];
    float2 c1 = tws[k3*67 + xb + 32];
    float2 gq[4];
    #pragma unroll
    for (int j=0; j<4; j++) gq[j] = Gsm[p][(e0+j)*NK3 + k3];
    if (k3 & 1){
      #pragma unroll
      for (int j=0; j<4; j++){
        O[0][j] = fmaf(gq[j].x, c0.x, O[0][j]); O[0][j] = fmaf(gq[j].y, c0.y, O[0][j]);
        O[1][j] = fmaf(gq[j].x, c1.x, O[1][j]); O[1][j] = fmaf(gq[j].y, c1.y, O[1][j]);
      }
    } else {
      #pragma unroll
      for (int j=0; j<4; j++){
        E[0][j] = fmaf(gq[j].x, c0.x, E[0][j]); E[0][j] = fmaf(gq[j].y, c0.y, E[0][j]);
        E[1][j] = fmaf(gq[j].x, c1.x, E[1][j]); E[1][j] = fmaf(gq[j].y, c1.y, E[1][j]);
      }
    }
  }
  #pragma unroll
  for (int q=0; q<4; q++){
    int x3 = xb + 32*q;
    union { uint4 u4; __half2 h2[4]; } lk;
    lk.u4 = *reinterpret_cast<const uint4*>(v + (pen<<10) + x3*DV);
    float vv[8];
    #pragma unroll
    for (int qq=0; qq<4; qq++){
      float2 f2 = __half22float2(lk.h2[qq]);
      vv[2*qq] = f2.x; vv[2*qq+1] = f2.y;
    }
    float s[4];
    #pragma unroll
    for (int j=0; j<4; j++){
      float e = E[q&1][j], o = O[q&1][j];
      s[j] = (q < 2) ? (e + o) : (e - o);
    }
    #pragma unroll
    for (int d=0; d<DV; d++)
      #pragma unroll
      for (int j=0; j<4; j++) s[j] = fmaf(vv[d], wr[d][j], s[j]);
    #pragma unroll
    for (int j=0; j<4; j++) vnr[p][e0+j][x3] = gelu_f(s[j]);
  }
  __syncthreads();
  float pwr[DV];
  #pragma unroll
  for (int e=0; e<DV; e++) pwr[e] = pws[e];
  float pbv = pbs;
  #pragma unroll
  for (int it=0; it<2; it++){
    int p2 = it*2 + (t>>7);
    int x3 = t & 127;
    float acc = pbv;
    #pragma unroll
    for (int e=0; e<DV; e++) acc = fmaf(vnr[p2][e][x3], pwr[e], acc);
    out[((pen_base + p2)<<7) + x3] = acc;
  }
}

// ------------------------------------------------------- axis-1 forward DFT
// grid (S1, 2); parity fold over x2 / x2+128 (chunk c / c+4)
__global__ __launch_bounds__(256) void k_stageB(const __half2* __restrict__ g,
    float2* __restrict__ h, const float2* __restrict__ twg){
  __shared__ unsigned int gsm[2][32*160];   // 40 KB
  int x1 = blockIdx.x;
  int k3o = blockIdx.y * 10;
  int t = threadIdx.x;
  int k2 = t >> 3, d = t & 7;
  float sgn = (k2 & 1) ? -1.0f : 1.0f;
  float ar[10], ai[10];
  #pragma unroll
  for (int j=0;j<10;j++){ ar[j]=0.f; ai[j]=0.f; }
  for (int c = 0; c < 4; c++){
    __syncthreads();
    const uint4* s0 = reinterpret_cast<const uint4*>(g + (size_t)(x1*S2 + c*32)*GPEN);
    const uint4* s1 = reinterpret_cast<const uint4*>(g + (size_t)(x1*S2 + (c+4)*32)*GPEN);
    uint4* d0 = reinterpret_cast<uint4*>(gsm[0]);
    uint4* d1 = reinterpret_cast<uint4*>(gsm[1]);
    #pragma unroll
    for (int r=0; r<5; r++){ d0[r*256 + t] = s0[r*256 + t]; d1[r*256 + t] = s1[r*256 + t]; }
    __syncthreads();
    if (t < 240){
      for (int x2l = 0; x2l < 32; x2l++){
        float2 tw = twg[k2*S2 + c*32 + x2l];
        const uint2* qlo = reinterpret_cast<const uint2*>(&gsm[0][x2l*160 + d*20 + k3o]);
        const uint2* qhi = reinterpret_cast<const uint2*>(&gsm[1][x2l*160 + d*20 + k3o]);
        #pragma unroll
        for (int jj=0; jj<5; jj++){
          uint2 ulo = qlo[jj], uhi = qhi[jj];
          float2 a0 = __half22float2(*reinterpret_cast<const __half2*>(&ulo.x));
          float2 b0 = __half22float2(*reinterpret_cast<const __half2*>(&uhi.x));
          float2 a1 = __half22float2(*reinterpret_cast<const __half2*>(&ulo.y));
          float2 b1 = __half22float2(*reinterpret_cast<const __half2*>(&uhi.y));
          float2 g0 = make_float2(fmaf(sgn, b0.x, a0.x), fmaf(sgn, b0.y, a0.y));
          float2 g1 = make_float2(fmaf(sgn, b1.x, a1.x), fmaf(sgn, b1.y, a1.y));
          cmac_fwd(ar[2*jj],   ai[2*jj],   g0, tw);
          cmac_fwd(ar[2*jj+1], ai[2*jj+1], g1, tw);
        }
      }
    }
  }
  if (t < 240){
    float2* hp = h + (size_t)((x1*NK2 + k2)*(DV*NK3) + d*NK3 + k3o);
    #pragma unroll
    for (int j=0;j<10;j++) hp[j] = make_float2(ar[j], ai[j]);
  }
}

// ------------------------------------------------------- axis-0 forward DFT
// parity fold over x1 / x1+128
__global__ __launch_bounds__(256) void k_stageC(const float2* __restrict__ h,
    float2* __restrict__ f, const float2* __restrict__ tw256){
  int idx = blockIdx.x*256 + threadIdx.x;
  if (idx >= NK1*HSLICE) return;
  int k1 = idx / HSLICE, r = idx % HSLICE;
  float sgn = (k1 & 1) ? -1.0f : 1.0f;
  float ar=0.f, ai=0.f;
  const float2* twp = &tw256[k1*S1];
  for (int x1=0; x1<128; x1++){
    float2 h1 = h[(size_t)x1*HSLICE + r];
    float2 h2 = h[(size_t)(x1+128)*HSLICE + r];
    float2 hv = make_float2(fmaf(sgn, h2.x, h1.x), fmaf(sgn, h2.y, h1.y));
    cmac_fwd(ar, ai, hv, twp[x1]);
  }
  f[idx] = make_float2(ar, ai);
}

// ------------------------------------------------------------- mode mixing
__global__ __launch_bounds__(256) void k_mix(const float2* __restrict__ f,
    const float* __restrict__ Rr, const float* __restrict__ Ri,
    float2* __restrict__ Rf){
  int idx = blockIdx.x*256 + threadIdx.x;
  if (idx >= NK1*HSLICE) return;
  int k12 = idx / (DV*NK3), r = idx % (DV*NK3);
  int e = r / NK3, k3 = r % NK3;
  const float2* fp  = &f[(size_t)k12*(DV*NK3) + k3];
  const float* rrp = &Rr[((size_t)k12*NK3 + k3)*64 + e];
  const float* rip = &Ri[((size_t)k12*NK3 + k3)*64 + e];
  float ar=0.f, ai=0.f;
  #pragma unroll
  for (int d=0; d<DV; d++){
    float2 fv = fp[d*NK3];
    float wr = rrp[d*DV], wi = rip[d*DV];
    ar = fmaf(fv.x, wr, ar); ar = fmaf(-fv.y, wi, ar);
    ai = fmaf(fv.x, wi, ai); ai = fmaf(fv.y, wr, ai);
  }
  const float sc = 1.1920928955078125e-7f; // 1/(256*256*128)
  Rf[idx] = make_float2(ar*sc, ai*sc);
}

// ------------------------------------------------------- axis-0 inverse DFT
// parity fold: one thread emits H[x1] and H[x1+128]
__global__ __launch_bounds__(256) void k_stageCi(const float2* __restrict__ Rf,
    float2* __restrict__ H, const float2* __restrict__ tw256){
  int idx = blockIdx.x*256 + threadIdx.x;   // exactly 128*4800 threads
  int x1 = idx / HSLICE, r = idx % HSLICE;
  float Er=0.f, Ei=0.f, Or=0.f, Oi=0.f;
  #pragma unroll
  for (int k1=0; k1<NK1; k1++){
    float2 a = Rf[(size_t)k1*HSLICE + r];
    float2 tw = tw256[k1*S1 + x1];
    if (k1 & 1) cmac_inv(Or, Oi, a, tw);
    else        cmac_inv(Er, Ei, a, tw);
  }
  H[(size_t)x1*HSLICE + r]        = make_float2(Er+Or, Ei+Oi);
  H[(size_t)(x1+128)*HSLICE + r]  = make_float2(Er-Or, Ei-Oi);
}

// ------------------------------------------------------- axis-1 inverse DFT
// parity fold: one thread-iter emits G[x2] and G[x2+128]
__global__ __launch_bounds__(320) void k_stageBi(const float2* __restrict__ H,
    __half2* __restrict__ G, const float2* __restrict__ twg){
  __shared__ float2 Hs[HSLICE];            // 38.4 KB
  int x1 = blockIdx.x;
  int t = threadIdx.x;                     // 320
  const float* Hf = (const float*)(H + (size_t)x1*HSLICE);
  float* Hsf = (float*)Hs;
  for (int i = t; i < HSLICE*2; i += 320) Hsf[i] = Hf[i];
  __syncthreads();
  int grp = t / 160, r = t % 160;
  for (int i = 0; i < 64; i++){
    int x2 = 2*i + grp;
    float Er=0.f, Ei=0.f, Or=0.f, Oi=0.f;
    #pragma unroll
    for (int k2=0; k2<NK2; k2++){
      float2 a = Hs[k2*160 + r];
      float2 tw = twg[k2*S2 + x2];
      if (k2 & 1) cmac_inv(Or, Oi, a, tw);
      else        cmac_inv(Er, Ei, a, tw);
    }
    size_t b = ((size_t)(x1*S2) + x2)*GPEN + r;
    G[b]                      = __floats2half2_rn(Er+Or, Ei+Oi);
    G[b + (size_t)128*GPEN]   = __floats2half2_rn(Er-Or, Ei-Oi);
  }
}

extern "C" void kernel_launch(void* const* d_in, const int* in_sizes, int n_in,
                              void* d_out, int out_size, void* d_ws, size_t ws_size,
                              hipStream_t stream){
  const float* x  = (const float*)d_in[0];
  const float* sw = (const float*)d_in[1];
  const float* sb = (const float*)d_in[2];
  const float* Rr[4] = {(const float*)d_in[3],(const float*)d_in[6],(const float*)d_in[9],(const float*)d_in[12]};
  const float* Ri[4] = {(const float*)d_in[4],(const float*)d_in[7],(const float*)d_in[10],(const float*)d_in[13]};
  const float* w[4]  = {(const float*)d_in[5],(const float*)d_in[8],(const float*)d_in[11],(const float*)d_in[14]};
  const float* pw = (const float*)d_in[15];
  const float* pb = (const float*)d_in[16];
  float* out = (float*)d_out;
  float* ws = (float*)d_ws;

  __half*  v    = (__half*)(ws + OFF_V);
  __half2* g    = (__half2*)(ws + OFF_G);
  float2* h     = (float2*)(ws + OFF_H);
  float2* f     = (float2*)(ws + OFF_F);
  float2* Rf    = (float2*)(ws + OFF_RF);
  float2* tw128 = (float2*)(ws + OFF_TW128);
  float2* tw256 = (float2*)(ws + OFF_TW256);

  k_twiddles<<<35, 256, 0, stream>>>(tw128, tw256);
  k_shallow<<<NPEN/PB, 256, 0, stream>>>(x, sw, sb, v, g, tw128);
  for (int L = 0; L < 4; L++){
    k_stageB <<<dim3(S1,2), 256, 0, stream>>>(g, h, tw256);
    k_stageC <<<(NK1*HSLICE + 255)/256, 256, 0, stream>>>(h, f, tw256);
    k_mix    <<<(NK1*HSLICE + 255)/256, 256, 0, stream>>>(f, Rr[L], Ri[L], Rf);
    k_stageCi<<<(128*HSLICE)/256, 256, 0, stream>>>(Rf, h, tw256);
    k_stageBi<<<S1, 320, 0, stream>>>(h, g, tw256);
    if (L < 3)
      k_combine<<<NPEN/PB, 256, 0, stream>>>(v, g, w[L], tw128);
    else
      k_final<<<NPEN/PB, 256, 0, stream>>>(v, g, w[L], pw, pb, out, tw128);
  }
}